// Round 17
// baseline (1709.402 us; speedup 1.0000x reference)
//
#include <hip/hip_runtime.h>
#include <cstdint>
#include <math.h>

// ---------------- problem constants ----------------
#define NSTEPS 64
#define NEGV   (-1.0e9f)

// d_out offsets (in floats): logits[4096][64][128], units[4096][64], ar[4096][1024], sel_num[4096]
#define OUT_L0 0
#define OUT_U0 33554432
#define OUT_A0 33816576
#define OUT_S0 38010880

// d_ws offsets (bytes)
#define WS_KF  0           // float [4096*128*32]  = 67108864 B
#define WS_KA  67108864    // double[4096*32]      = 1048576 B
#define WS_M2  68157440    // double[256*32]       = 65536 B
#define WS_VPB 68222976    // double[256]          = 2048 B

// JAX PRNG mode: 1 = threefry_partitionable (modern default), 0 = legacy split-counter
#define JAX_PARTITIONABLE 1

// ---------------- threefry2x32 (exact JAX algorithm) ----------------
__device__ __forceinline__ uint32_t rotl32(uint32_t x, int r){ return (x << r) | (x >> (32 - r)); }

__device__ __forceinline__ void threefry2x32(uint32_t k0, uint32_t k1,
                                             uint32_t x0, uint32_t x1,
                                             uint32_t &o0, uint32_t &o1){
  const uint32_t ks2 = k0 ^ k1 ^ 0x1BD11BDAu;
  x0 += k0; x1 += k1;
#define TFR(r) { x0 += x1; x1 = rotl32(x1, (r)); x1 ^= x0; }
  TFR(13) TFR(15) TFR(26) TFR(6)
  x0 += k1;  x1 += ks2 + 1u;
  TFR(17) TFR(29) TFR(16) TFR(24)
  x0 += ks2; x1 += k0 + 2u;
  TFR(13) TFR(15) TFR(26) TFR(6)
  x0 += k0;  x1 += k1 + 3u;
  TFR(17) TFR(29) TFR(16) TFR(24)
  x0 += k1;  x1 += ks2 + 4u;
  TFR(13) TFR(15) TFR(26) TFR(6)
  x0 += ks2; x1 += k0 + 5u;
#undef TFR
  o0 = x0; o1 = x1;
}

// bits -> uniform(tiny,1) -> gumbel. Bit-exact jax mantissa trick; f32 HW logs
// (ref computes gumbel in f32 itself; validated R10/R11/R15, absmax 0.125).
__device__ __forceinline__ float gumbel_bits_f32(uint32_t bits){
  float f = __uint_as_float(0x3F800000u | (bits >> 9)) - 1.0f;
  float u = (f == 0.0f) ? 1.17549435e-38f : f;
  return -__logf(-__logf(u));
}

// per-element random bits for step-key (k0,k1), flat index j (B*E = 524288 < 2^32)
__device__ __forceinline__ uint32_t jax_bits(uint32_t k0, uint32_t k1, uint32_t j){
#if JAX_PARTITIONABLE
  uint32_t o0, o1;
  threefry2x32(k0, k1, 0u, j, o0, o1);
  return o0 ^ o1;
#else
  const uint32_t HALF = 262144u;
  uint32_t o0, o1;
  if (j < HALF){ threefry2x32(k0, k1, j, j + HALF, o0, o1); return o0; }
  else         { threefry2x32(k0, k1, j - HALF, j, o0, o1); return o1; }
#endif
}

// ---------------- kernel 1 (R17 rewrite): key_feat via w-in-registers ----------------
// Old version: 4096 LDS b128 reads/thread (32-distinct-bank wlds + elds). New: conv_w
// quarter in 8 float4 regs (t = k*8+oct layout), elds reads are 8-address broadcasts,
// octant tree-reduce via 3 intra-wave shuffles. Target: HBM floor (~81us for 512 MB ee).
__launch_bounds__(256, 2)
__global__ void k_keyfeat(const float* __restrict__ ee, const float* __restrict__ convw,
                          const float* __restrict__ convb, float* __restrict__ kf){
  __shared__ float elds[16 * 256];   // 16 (b,e)-rows, 16 KB
  const int t = threadIdx.x;
  const int k = t >> 3;        // 0..31
  const int oct = t & 7;       // 0..7 (32-d octant; bits 0-2 of lane -> shuffle-reducible)
  float4 wv[8];
  #pragma unroll
  for (int j = 0; j < 8; ++j)
    wv[j] = *reinterpret_cast<const float4*>(&convw[k * 256 + oct * 32 + j * 4]);
  const float bk = convb[k];
  const long rowbase = (long)blockIdx.x * 256;
  for (int tile = 0; tile < 16; ++tile){
    const long r0 = rowbase + tile * 16;
    __syncthreads();                   // previous tile's readers done
    #pragma unroll
    for (int j = 0; j < 4; ++j){
      int f = t + 256 * j;             // 1024 float4
      int rr = f >> 6, d4 = (f & 63) << 2;
      *reinterpret_cast<float4*>(&elds[rr * 256 + d4]) =
        *reinterpret_cast<const float4*>(&ee[(r0 + rr) * 256 + d4]);
    }
    __syncthreads();
    #pragma unroll 4
    for (int r = 0; r < 16; ++r){
      float c0 = 0.f, c1 = 0.f, c2 = 0.f, c3 = 0.f;
      #pragma unroll
      for (int j = 0; j < 8; ++j){
        float4 e4 = *reinterpret_cast<const float4*>(&elds[r * 256 + oct * 32 + j * 4]);
        c0 = fmaf(e4.x, wv[j].x, c0); c1 = fmaf(e4.y, wv[j].y, c1);
        c2 = fmaf(e4.z, wv[j].z, c2); c3 = fmaf(e4.w, wv[j].w, c3);
      }
      float s = (c0 + c1) + (c2 + c3);
      s += __shfl_xor(s, 1);
      s += __shfl_xor(s, 2);
      s += __shfl_xor(s, 4);
      if (oct == 0) kf[(r0 + r) * 32 + k] = s + bk;
    }
  }
}

// ---------------- kernel 2: key_avg[b,k] = sum_e kf / unit_num[b] (f64) ----------------
__global__ void k_keyavg(const float* __restrict__ kf, const float* __restrict__ unum,
                         double* __restrict__ ka){
  const int t = threadIdx.x;
  const int b = blockIdx.x * 8 + (t >> 5), k = t & 31;
  const float* p = kf + (long)b * 4096 + k;
  double s = 0.0;
  #pragma unroll 8
  for (int e = 0; e < 128; ++e) s += (double)p[e * 32];
  ka[b * 32 + k] = s / (double)unum[b];
}

// ---------------- kernel 3 (R17 rewrite): M2 = fc1_w @ proj_w, v_pb = fc1_w @ proj_b ----
// Old: 33 blocks (223 CUs idle) x 1024-deep serial f64 chain. New: 257 blocks,
// 8-chunk split + LDS reduce (f64 reorder noise ~1e-16, irrelevant).
__global__ void k_m2(const float* __restrict__ fc1w, const float* __restrict__ projw,
                     const float* __restrict__ projb, double* __restrict__ m2,
                     double* __restrict__ vpb){
  const int t = threadIdx.x;
  if (blockIdx.x < 256){
    const int o = blockIdx.x, k = t & 31, ch = t >> 5;
    __shared__ double red[8][32];
    double s = 0.0;
    const float* fw = &fc1w[o * 1024 + ch * 128];
    const float* pw = &projw[(ch * 128) * 32 + k];
    #pragma unroll 4
    for (int d = 0; d < 128; ++d)
      s = fma((double)fw[d], (double)pw[d * 32], s);
    red[ch][k] = s;
    __syncthreads();
    if (ch == 0){
      double tot = 0.0;
      #pragma unroll
      for (int c = 0; c < 8; ++c) tot += red[c][k];
      m2[o * 32 + k] = tot;
    }
  } else {
    const int o = t;
    double s = 0.0;
    for (int d = 0; d < 1024; ++d)
      s = fma((double)fc1w[o * 1024 + d], (double)projb[d], s);
    vpb[o] = s;
  }
}

// ---------------- scan kernel: R16 BYTE-IDENTICAL (proven 1235us, no spill) ----------------
// SPILL LAW: no fences, 5 barriers, no D load-shape changes, gl stays f64.
// LDS layout (bytes):
#define SM_KF   0        // float4 [8*128*8] swizzled key_feat        131072
#define SM_X    131072   // float  [8][288] (chunked 36-pad relu(z))    9216
#define SM_GL   140288   // double [8][128] gates                       8192
#define SM_H    148480   // double [8][32]  h f64 (for D)               2048
#define SM_OV   150528   // double [8][32]  epilogue sacc               2048
#define SM_KA   152576   // double [8][32]  key_avg                     2048
#define SM_KEYS 154624   // uint2  [64]                                  512
#define SM_GT   155136   // double [8]      gate                          64
#define SM_CNT  155200   // double [8]      count                         64
#define SM_HF   155264   // float  [8][32]  h f32 (for B)               1024
#define SM_OVF  156288   // float  [8][32]  out vec f32 (for G)         1024
#define SM_SIZE 157312

__launch_bounds__(512, 2)
__global__ void k_scan(const float* __restrict__ ar0, const void* __restrict__ selmask,
                       const float* __restrict__ fc1w, const float* __restrict__ fc1b,
                       const float* __restrict__ wih, const float* __restrict__ whh,
                       const float* __restrict__ bih, const float* __restrict__ bhh,
                       const float* __restrict__ projw, const float* __restrict__ projb,
                       const float* __restrict__ kfg, const double* __restrict__ kag,
                       const double* __restrict__ m2g, const double* __restrict__ vpbg,
                       float* __restrict__ outp){
  extern __shared__ char smem[];
  float4* kf4 = (float4*)(smem + SM_KF);
  float*  xk  = (float*) (smem + SM_X);
  double* gl  = (double*)(smem + SM_GL);
  double* hld = (double*)(smem + SM_H);
  double* ovd = (double*)(smem + SM_OV);
  double* kav = (double*)(smem + SM_KA);
  uint2*  keys= (uint2*) (smem + SM_KEYS);
  double* gted= (double*)(smem + SM_GT);
  double* cntd= (double*)(smem + SM_CNT);
  float*  hf  = (float*) (smem + SM_HF);
  float*  ovf = (float*) (smem + SM_OVF);

  const int t  = threadIdx.x;
  const int w  = t >> 6;        // wave id == row within block
  const int ln = t & 63;        // lane
  const int o  = t & 255;       // z/x column ownership
  const int rh = t >> 8;        // row half {0,1} -> rows rh*4..rh*4+3
  const int g  = t >> 2;        // gate id (0..127)
  const int sh = t & 3;         // d-quarter split
  const long blkrow = (long)blockIdx.x * 8;

  // step keys: key_i = threefry((0,42),(0,i))  (fold_in semantics)
  if (t < NSTEPS){
    uint32_t o0, o1; threefry2x32(0u, 42u, 0u, (uint32_t)t, o0, o1);
    keys[t] = make_uint2(o0, o1);
  }
  // stage ar0 rows into kf area (reused before kf load)
  float* arst = (float*)(smem + SM_KF);   // [8][1024]
  #pragma unroll
  for (int j = 0; j < 4; ++j){            // 8192 floats = 2048 float4 / 512
    int f = t + 512 * j;
    int r = f >> 8, d4 = (f & 255) << 2;
    *reinterpret_cast<float4*>(&arst[r * 1024 + d4]) =
      *reinterpret_cast<const float4*>(&ar0[(blkrow + r) * 1024 + d4]);
  }
  if (t < 256){
    int r = t >> 5, k = t & 31;
    kav[r * 32 + k] = kag[(blkrow + r) * 32 + k];
  }
  __syncthreads();

  // z0[r][o] = fc1_w[o,:]·ar0[r,:] + fc1_b[o]   (f32 chains, f64 combine)
  double z[4];
  {
    float a[4][4] = {{0.f,0.f,0.f,0.f},{0.f,0.f,0.f,0.f},{0.f,0.f,0.f,0.f},{0.f,0.f,0.f,0.f}};
    const float* wr = fc1w + (long)o * 1024;
    #pragma unroll 4
    for (int d4 = 0; d4 < 1024; d4 += 4){
      float4 w4 = *reinterpret_cast<const float4*>(&wr[d4]);
      #pragma unroll
      for (int q = 0; q < 4; ++q){
        float4 av = *reinterpret_cast<const float4*>(&arst[(rh * 4 + q) * 1024 + d4]);
        a[q][0] = fmaf(w4.x, av.x, a[q][0]); a[q][1] = fmaf(w4.y, av.y, a[q][1]);
        a[q][2] = fmaf(w4.z, av.z, a[q][2]); a[q][3] = fmaf(w4.w, av.w, a[q][3]);
      }
    }
    const double bb = (double)fc1b[o];
    #pragma unroll
    for (int q = 0; q < 4; ++q)
      z[q] = ((double)a[q][0] + (double)a[q][1]) + ((double)a[q][2] + (double)a[q][3]) + bb;
  }
  __syncthreads();

  // key_feat tiles -> LDS, float4-slot XOR swizzle (slot ^= e&7) to break stride-128B bank alias
  #pragma unroll
  for (int j = 0; j < 16; ++j){
    int f = t + 512 * j;                 // 8192 float4s
    int r = f >> 10, rem = f & 1023;
    int e = rem >> 3, sl = rem & 7;
    float4 v = *reinterpret_cast<const float4*>(&kfg[((blkrow + r) * 128 + e) * 32 + sl * 4]);
    kf4[(r * 128 + e) * 8 + (sl ^ (e & 7))] = v;
  }

  // register preloads
  float m2rf[32];
  #pragma unroll
  for (int k = 0; k < 32; ++k) m2rf[k] = (float)m2g[o * 32 + k];
  const double vpbr = vpbg[o];
  float4 w4r[16];
  #pragma unroll
  for (int j = 0; j < 16; ++j)
    w4r[j] = *reinterpret_cast<const float4*>(&wih[g * 256 + sh * 64 + j * 4]);
  float whr[8];
  #pragma unroll
  for (int jk = 0; jk < 8; ++jk) whr[jk] = whh[g * 32 + sh * 8 + jk];
  const double bsum = (double)bih[g] + (double)bhh[g];

  // ---- mask load with dtype auto-detect (bool as u8 bytes vs 32-bit words) ----
  uint64_t m0, m1;
  {
    const uint32_t w0 = *(const uint32_t*)selmask;
    if (w0 == 0x01010101u){
      const uint8_t* m8 = (const uint8_t*)selmask;
      m0 = __ballot(m8[(blkrow + w) * 128 + ln] != 0);
      m1 = __ballot(m8[(blkrow + w) * 128 + 64 + ln] != 0);
    } else {
      const uint32_t* m32 = (const uint32_t*)selmask;
      m0 = __ballot(m32[(blkrow + w) * 128 + ln] != 0);
      m1 = __ballot(m32[(blkrow + w) * 128 + 64 + ln] != 0);
    }
  }
  bool  isend = false;
  float selnum = (float)NSTEPS;   // used by ln==0
  double cnt_reg = 0.0;           // ln==0
  float  c_regf = 0.f;            // lanes < 32 (k = ln); f32 cell state (ref is f32 too)
  double sacc_reg = 0.0;          // lanes < 32
  if (ln < 32){ hld[w * 32 + ln] = 0.0; hf[w * 32 + ln] = 0.f; }
  __syncthreads();

  #pragma unroll 1
  for (int i = 0; i < NSTEPS; ++i){
    // --- A: x = relu(z) -> LDS (f32, matching reference quantization point) ---
    #pragma unroll
    for (int q = 0; q < 4; ++q){
      double zv = z[q];
      float xv = zv > 0.0 ? (float)zv : 0.0f;
      xk[(rh * 4 + q) * 288 + (o >> 5) * 36 + (o & 31)] = xv;
    }
    __syncthreads();

    // --- B: gates = w_ih@x + w_hh@h + b  (all-f32 chains + f32 combine;
    //     gl store casts to f64 — gl dtype unchanged, C/D untouched) ---
    {
      float acc[8] = {0.f,0.f,0.f,0.f,0.f,0.f,0.f,0.f};
      #pragma unroll
      for (int i4 = 0; i4 < 64; i4 += 4){
        const int d = sh * 64 + i4;
        const int xi = (d >> 5) * 36 + (d & 31);
        const float4 w4 = w4r[i4 >> 2];
        #pragma unroll
        for (int r = 0; r < 8; ++r){
          float4 xv = *reinterpret_cast<const float4*>(&xk[r * 288 + xi]);
          acc[r] = fmaf(w4.x, xv.x, fmaf(w4.y, xv.y, fmaf(w4.z, xv.z, fmaf(w4.w, xv.w, acc[r]))));
        }
      }
      #pragma unroll
      for (int r = 0; r < 8; ++r){
        float hacc = 0.f;
        #pragma unroll
        for (int q2 = 0; q2 < 2; ++q2){
          float4 hv = *reinterpret_cast<const float4*>(&hf[r * 32 + sh * 8 + q2 * 4]);
          const float* wp = &whr[q2 * 4];
          hacc = fmaf(wp[0], hv.x, fmaf(wp[1], hv.y,
                 fmaf(wp[2], hv.z, fmaf(wp[3], hv.w, hacc))));
        }
        acc[r] += hacc;
      }
      #pragma unroll
      for (int r = 0; r < 8; ++r){
        acc[r] += __shfl_xor(acc[r], 1);
        acc[r] += __shfl_xor(acc[r], 2);
      }
      if (sh == 0){
        #pragma unroll
        for (int r = 0; r < 8; ++r) gl[r * 128 + g] = (double)acc[r] + bsum;
      }
    }
    __syncthreads();

    // --- C: LSTM pointwise in f32 (v_exp_f32; R10/R11-validated). Publishes f64+f32 h. ---
    if (ln < 32){
      const int k = ln;
      float gi = (float)gl[w * 128 + k],      gf = (float)gl[w * 128 + 32 + k];
      float gc = (float)gl[w * 128 + 64 + k], go = (float)gl[w * 128 + 96 + k];
      float ig = 1.f / (1.f + __expf(-gi));
      float fg = 1.f / (1.f + __expf(-gf));
      float og = 1.f / (1.f + __expf(-go));
      float tg = 2.f / (1.f + __expf(-2.f * gc)) - 1.f;     // tanh(gg)
      c_regf = fg * c_regf + ig * tg;
      float tc = 2.f / (1.f + __expf(-2.f * c_regf)) - 1.f; // tanh(c)
      float hv = og * tc;
      hld[w * 32 + k] = (double)hv;
      hf[w * 32 + k] = hv;
    }
    __syncthreads();

    // --- D: logits (f64) + masked-logits output write (R11/R15 byte-identical) ---
    double lg[2];
    const size_t lbase = ((size_t)(blkrow + w) * NSTEPS + i) * 128;
    #pragma unroll
    for (int j = 0; j < 2; ++j){
      const int e = ln + 64 * j;
      const int sw = e & 7;
      const int base = (w * 128 + e) * 8;
      double acc = 0.0;
      #pragma unroll
      for (int l = 0; l < 8; ++l){
        float4 v = kf4[base + (l ^ sw)];
        const double* hp = &hld[w * 32 + l * 4];
        acc = fma((double)v.x, hp[0], acc);
        acc = fma((double)v.y, hp[1], acc);
        acc = fma((double)v.z, hp[2], acc);
        acc = fma((double)v.w, hp[3], acc);
      }
      lg[j] = acc;
      bool bit = (j == 0) ? ((m0 >> e) & 1ull) : ((m1 >> (e - 64)) & 1ull);
      outp[OUT_L0 + lbase + e] = bit ? (float)acc : NEGV;
    }

    // --- E: gumbel-argmax in f32 (R15-validated; thread-local leaf region) ---
    float bs = -3.0e38f; int bi = 1 << 20;
    const uint2 kk = keys[i];
    #pragma unroll
    for (int j = 0; j < 2; ++j){
      const int e = ln + 64 * j;
      bool bit = (j == 0) ? ((m0 >> e) & 1ull) : ((m1 >> (e - 64)) & 1ull);
      if (bit){
        uint32_t bits = jax_bits(kk.x, kk.y, (uint32_t)((blkrow + w) * 128 + e));
        float sv = (float)lg[j] + gumbel_bits_f32(bits);
        if (sv > bs || (sv == bs && e < bi)){ bs = sv; bi = e; }
      }
    }
    #pragma unroll
    for (int m = 1; m < 64; m <<= 1){
      float os = __shfl_xor(bs, m);
      int   oi = __shfl_xor(bi, m);
      if (os > bs || (os == bs && oi < bi)){ bs = os; bi = oi; }
    }
    const int uid = bi;

    // --- F: state updates (R11-exact; publishes f32 out-vec for G) ---
    {
      const bool new_end = (uid == 127);
      if (ln == 0 && new_end && !isend) selnum = (float)i;
      isend = isend || new_end;
      const double gate = isend ? 0.0 : 1.0;
      if (uid < 64) m0 &= ~(1ull << uid); else m1 &= ~(1ull << (uid - 64));
      if (ln == 0){
        gted[w] = gate;
        cnt_reg += gate;
        outp[OUT_U0 + (size_t)(blkrow + w) * NSTEPS + i] = (float)uid;
      }
      if (ln < 32){
        const int k = ln;
        float4 v = kf4[(w * 128 + uid) * 8 + ((k >> 2) ^ (uid & 7))];
        const int s3 = k & 3;
        float kv = (s3 == 0) ? v.x : (s3 == 1) ? v.y : (s3 == 2) ? v.z : v.w;
        double ov = (double)kv - kav[w * 32 + k];
        ovf[w * 32 + k] = (float)ov;
        sacc_reg += gate * ov;
      }
    }
    __syncthreads();

    // --- G: z += gate*(M2[o,:]·out + v_pb[o])  (f32 delta + f64 carry — R11-exact) ---
    #pragma unroll
    for (int q = 0; q < 4; ++q){
      const int r = rh * 4 + q;
      if (gted[r] != 0.0){
        float zf = 0.f;
        #pragma unroll
        for (int j8 = 0; j8 < 8; ++j8){
          float4 ov4 = *reinterpret_cast<const float4*>(&ovf[r * 32 + j8 * 4]);  // uniform
          const float* mp = &m2rf[j8 * 4];
          zf = fmaf(mp[0], ov4.x, fmaf(mp[1], ov4.y,
               fmaf(mp[2], ov4.z, fmaf(mp[3], ov4.w, zf))));
        }
        z[q] += (double)zf + vpbr;
      }
    }
    __syncthreads();
  }

  // -------- epilogue: sel_num, s_acc publish, final ar --------
  if (ln < 32) ovd[w * 32 + ln] = sacc_reg;
  if (ln == 0){
    cntd[w] = cnt_reg;
    outp[OUT_S0 + (blkrow + w)] = selnum;
  }
  __syncthreads();

  #pragma unroll
  for (int jj = 0; jj < 2; ++jj){
    const int dd = t * 2 + jj;
    float4 pw4[8];
    #pragma unroll
    for (int q = 0; q < 8; ++q)
      pw4[q] = *reinterpret_cast<const float4*>(&projw[dd * 32 + q * 4]);
    const double pb = (double)projb[dd];
    #pragma unroll
    for (int r = 0; r < 8; ++r){
      const double* sp = &ovd[r * 32];
      double acc = 0.0;
      #pragma unroll
      for (int q = 0; q < 8; ++q){
        acc = fma((double)pw4[q].x, sp[q * 4 + 0], acc);
        acc = fma((double)pw4[q].y, sp[q * 4 + 1], acc);
        acc = fma((double)pw4[q].z, sp[q * 4 + 2], acc);
        acc = fma((double)pw4[q].w, sp[q * 4 + 3], acc);
      }
      double arv = (double)ar0[(blkrow + r) * 1024 + dd] + acc + pb * cntd[r];
      outp[OUT_A0 + (size_t)(blkrow + r) * 1024 + dd] = (float)arv;
    }
  }
}

// ---------------- launcher ----------------
extern "C" void kernel_launch(void* const* d_in, const int* in_sizes, int n_in,
                              void* d_out, int out_size, void* d_ws, size_t ws_size,
                              hipStream_t stream){
  const float*   ar0   = (const float*)d_in[0];
  const float*   ee    = (const float*)d_in[1];
  const void*    msk   = (const void*)d_in[2];
  const float*   unum  = (const float*)d_in[3];
  const float*   convw = (const float*)d_in[4];
  const float*   convb = (const float*)d_in[5];
  const float*   fc1w  = (const float*)d_in[6];
  const float*   fc1b  = (const float*)d_in[7];
  const float*   wih   = (const float*)d_in[8];
  const float*   whh   = (const float*)d_in[9];
  const float*   bih   = (const float*)d_in[10];
  const float*   bhh   = (const float*)d_in[11];
  const float*   projw = (const float*)d_in[12];
  const float*   projb = (const float*)d_in[13];
  float* out = (float*)d_out;
  char*  ws  = (char*)d_ws;

  float*  kf  = (float*) (ws + WS_KF);
  double* ka  = (double*)(ws + WS_KA);
  double* m2  = (double*)(ws + WS_M2);
  double* vpb = (double*)(ws + WS_VPB);

  k_keyfeat<<<2048, 256, 0, stream>>>(ee, convw, convb, kf);
  k_keyavg <<<512, 256, 0, stream>>>(kf, unum, ka);
  k_m2     <<<257, 256, 0, stream>>>(fc1w, projw, projb, m2, vpb);

  (void)hipFuncSetAttribute((const void*)k_scan,
                            hipFuncAttributeMaxDynamicSharedMemorySize, SM_SIZE);
  k_scan<<<512, 512, SM_SIZE, stream>>>(ar0, msk, fc1w, fc1b, wih, whh, bih, bhh,
                                        projw, projb, kf, ka, m2, vpb, out);
}

// Round 18
// 1466.932 us; speedup vs baseline: 1.1653x; 1.1653x over previous
//
#include <hip/hip_runtime.h>
#include <cstdint>
#include <math.h>

// ---------------- problem constants ----------------
#define NSTEPS 64
#define NEGV   (-1.0e9f)

// d_out offsets (in floats): logits[4096][64][128], units[4096][64], ar[4096][1024], sel_num[4096]
#define OUT_L0 0
#define OUT_U0 33554432
#define OUT_A0 33816576
#define OUT_S0 38010880

// d_ws offsets (bytes)
#define WS_KF  0           // float [4096*128*32]  = 67108864 B
#define WS_KA  67108864    // double[4096*32]      = 1048576 B
#define WS_M2  68157440    // double[256*32]       = 65536 B
#define WS_VPB 68222976    // double[256]          = 2048 B

// JAX PRNG mode: 1 = threefry_partitionable (modern default), 0 = legacy split-counter
#define JAX_PARTITIONABLE 1

// ---------------- threefry2x32 (exact JAX algorithm) ----------------
__device__ __forceinline__ uint32_t rotl32(uint32_t x, int r){ return (x << r) | (x >> (32 - r)); }

__device__ __forceinline__ void threefry2x32(uint32_t k0, uint32_t k1,
                                             uint32_t x0, uint32_t x1,
                                             uint32_t &o0, uint32_t &o1){
  const uint32_t ks2 = k0 ^ k1 ^ 0x1BD11BDAu;
  x0 += k0; x1 += k1;
#define TFR(r) { x0 += x1; x1 = rotl32(x1, (r)); x1 ^= x0; }
  TFR(13) TFR(15) TFR(26) TFR(6)
  x0 += k1;  x1 += ks2 + 1u;
  TFR(17) TFR(29) TFR(16) TFR(24)
  x0 += ks2; x1 += k0 + 2u;
  TFR(13) TFR(15) TFR(26) TFR(6)
  x0 += k0;  x1 += k1 + 3u;
  TFR(17) TFR(29) TFR(16) TFR(24)
  x0 += k1;  x1 += ks2 + 4u;
  TFR(13) TFR(15) TFR(26) TFR(6)
  x0 += ks2; x1 += k0 + 5u;
#undef TFR
  o0 = x0; o1 = x1;
}

// bits -> uniform(tiny,1) -> gumbel. Bit-exact jax mantissa trick; f32 HW logs
// (ref computes gumbel in f32 itself; validated R10/R11/R15/R16, absmax 0.125).
__device__ __forceinline__ float gumbel_bits_f32(uint32_t bits){
  float f = __uint_as_float(0x3F800000u | (bits >> 9)) - 1.0f;
  float u = (f == 0.0f) ? 1.17549435e-38f : f;
  return -__logf(-__logf(u));
}

// per-element random bits for step-key (k0,k1), flat index j (B*E = 524288 < 2^32)
__device__ __forceinline__ uint32_t jax_bits(uint32_t k0, uint32_t k1, uint32_t j){
#if JAX_PARTITIONABLE
  uint32_t o0, o1;
  threefry2x32(k0, k1, 0u, j, o0, o1);
  return o0 ^ o1;
#else
  const uint32_t HALF = 262144u;
  uint32_t o0, o1;
  if (j < HALF){ threefry2x32(k0, k1, j, j + HALF, o0, o1); return o0; }
  else         { threefry2x32(k0, k1, j - HALF, j, o0, o1); return o1; }
#endif
}

// ---------------- kernel 1: key_feat (R16/R2 version — R17 rewrite regressed, reverted) ----
__launch_bounds__(256, 4)
__global__ void k_keyfeat(const float* __restrict__ ee, const float* __restrict__ convw,
                          const float* __restrict__ convb, float* __restrict__ kf){
  __shared__ float wlds[32 * 260];   // conv_w [k][d], row-padded to 260
  __shared__ float elds[8 * 256];    // 8 entity rows
  const int t = threadIdx.x;
  for (int j = 0; j < 32; ++j){
    int idx = t + 256 * j;            // 8192 = 32*256
    int k = idx >> 8, d = idx & 255;
    wlds[k * 260 + d] = convw[idx];
  }
  __syncthreads();
  const int r8 = t >> 5, k = t & 31;
  const float bk = convb[k];
  const long rowbase = (long)blockIdx.x * 256;
  for (int it = 0; it < 32; ++it){
    long r0 = rowbase + it * 8;
    #pragma unroll
    for (int j = 0; j < 2; ++j){
      int f = t + 256 * j;            // 512 float4s
      int rr = f >> 6, d4 = (f & 63) << 2;
      *reinterpret_cast<float4*>(&elds[rr * 256 + d4]) =
        *reinterpret_cast<const float4*>(&ee[(r0 + rr) * 256 + d4]);
    }
    __syncthreads();
    float c0 = 0.f, c1 = 0.f, c2 = 0.f, c3 = 0.f;
    #pragma unroll 8
    for (int d4 = 0; d4 < 256; d4 += 4){
      float4 e4 = *reinterpret_cast<const float4*>(&elds[r8 * 256 + d4]);
      float4 w4 = *reinterpret_cast<const float4*>(&wlds[k * 260 + d4]);
      c0 = fmaf(e4.x, w4.x, c0); c1 = fmaf(e4.y, w4.y, c1);
      c2 = fmaf(e4.z, w4.z, c2); c3 = fmaf(e4.w, w4.w, c3);
    }
    double s = ((double)c0 + (double)c1) + ((double)c2 + (double)c3) + (double)bk;
    kf[(r0 + r8) * 32 + k] = (float)s;
    __syncthreads();
  }
}

// ---------------- kernel 2: key_avg[b,k] = sum_e kf / unit_num[b] (f64) ----------------
__global__ void k_keyavg(const float* __restrict__ kf, const float* __restrict__ unum,
                         double* __restrict__ ka){
  const int t = threadIdx.x;
  const int b = blockIdx.x * 8 + (t >> 5), k = t & 31;
  const float* p = kf + (long)b * 4096 + k;
  double s = 0.0;
  #pragma unroll 8
  for (int e = 0; e < 128; ++e) s += (double)p[e * 32];
  ka[b * 32 + k] = s / (double)unum[b];
}

// ---------------- kernel 3: M2 = fc1_w @ proj_w, v_pb = fc1_w @ proj_b (R16 version) ----
__global__ void k_m2(const float* __restrict__ fc1w, const float* __restrict__ projw,
                     const float* __restrict__ projb, double* __restrict__ m2,
                     double* __restrict__ vpb){
  const int t = threadIdx.x;
  if (blockIdx.x < 32){
    const int o = blockIdx.x * 8 + (t >> 5), k = t & 31;
    double s = 0.0;
    for (int d = 0; d < 1024; ++d)
      s = fma((double)fc1w[o * 1024 + d], (double)projw[d * 32 + k], s);
    m2[o * 32 + k] = s;
  } else {
    const int o = t;
    double s = 0.0;
    for (int d = 0; d < 1024; ++d)
      s = fma((double)fc1w[o * 1024 + d], (double)projb[d], s);
    vpb[o] = s;
  }
}

// ---------------- scan kernel: R16 BYTE-IDENTICAL (proven 1235us, no spill) ----------------
// SPILL LAW: no fences, 5 barriers, no D load-shape changes, gl stays f64.
// LDS layout (bytes):
#define SM_KF   0        // float4 [8*128*8] swizzled key_feat        131072
#define SM_X    131072   // float  [8][288] (chunked 36-pad relu(z))    9216
#define SM_GL   140288   // double [8][128] gates                       8192
#define SM_H    148480   // double [8][32]  h f64 (for D)               2048
#define SM_OV   150528   // double [8][32]  epilogue sacc               2048
#define SM_KA   152576   // double [8][32]  key_avg                     2048
#define SM_KEYS 154624   // uint2  [64]                                  512
#define SM_GT   155136   // double [8]      gate                          64
#define SM_CNT  155200   // double [8]      count                         64
#define SM_HF   155264   // float  [8][32]  h f32 (for B)               1024
#define SM_OVF  156288   // float  [8][32]  out vec f32 (for G)         1024
#define SM_SIZE 157312

__launch_bounds__(512, 2)
__global__ void k_scan(const float* __restrict__ ar0, const void* __restrict__ selmask,
                       const float* __restrict__ fc1w, const float* __restrict__ fc1b,
                       const float* __restrict__ wih, const float* __restrict__ whh,
                       const float* __restrict__ bih, const float* __restrict__ bhh,
                       const float* __restrict__ projw, const float* __restrict__ projb,
                       const float* __restrict__ kfg, const double* __restrict__ kag,
                       const double* __restrict__ m2g, const double* __restrict__ vpbg,
                       float* __restrict__ outp){
  extern __shared__ char smem[];
  float4* kf4 = (float4*)(smem + SM_KF);
  float*  xk  = (float*) (smem + SM_X);
  double* gl  = (double*)(smem + SM_GL);
  double* hld = (double*)(smem + SM_H);
  double* ovd = (double*)(smem + SM_OV);
  double* kav = (double*)(smem + SM_KA);
  uint2*  keys= (uint2*) (smem + SM_KEYS);
  double* gted= (double*)(smem + SM_GT);
  double* cntd= (double*)(smem + SM_CNT);
  float*  hf  = (float*) (smem + SM_HF);
  float*  ovf = (float*) (smem + SM_OVF);

  const int t  = threadIdx.x;
  const int w  = t >> 6;        // wave id == row within block
  const int ln = t & 63;        // lane
  const int o  = t & 255;       // z/x column ownership
  const int rh = t >> 8;        // row half {0,1} -> rows rh*4..rh*4+3
  const int g  = t >> 2;        // gate id (0..127)
  const int sh = t & 3;         // d-quarter split
  const long blkrow = (long)blockIdx.x * 8;

  // step keys: key_i = threefry((0,42),(0,i))  (fold_in semantics)
  if (t < NSTEPS){
    uint32_t o0, o1; threefry2x32(0u, 42u, 0u, (uint32_t)t, o0, o1);
    keys[t] = make_uint2(o0, o1);
  }
  // stage ar0 rows into kf area (reused before kf load)
  float* arst = (float*)(smem + SM_KF);   // [8][1024]
  #pragma unroll
  for (int j = 0; j < 4; ++j){            // 8192 floats = 2048 float4 / 512
    int f = t + 512 * j;
    int r = f >> 8, d4 = (f & 255) << 2;
    *reinterpret_cast<float4*>(&arst[r * 1024 + d4]) =
      *reinterpret_cast<const float4*>(&ar0[(blkrow + r) * 1024 + d4]);
  }
  if (t < 256){
    int r = t >> 5, k = t & 31;
    kav[r * 32 + k] = kag[(blkrow + r) * 32 + k];
  }
  __syncthreads();

  // z0[r][o] = fc1_w[o,:]·ar0[r,:] + fc1_b[o]   (f32 chains, f64 combine)
  double z[4];
  {
    float a[4][4] = {{0.f,0.f,0.f,0.f},{0.f,0.f,0.f,0.f},{0.f,0.f,0.f,0.f},{0.f,0.f,0.f,0.f}};
    const float* wr = fc1w + (long)o * 1024;
    #pragma unroll 4
    for (int d4 = 0; d4 < 1024; d4 += 4){
      float4 w4 = *reinterpret_cast<const float4*>(&wr[d4]);
      #pragma unroll
      for (int q = 0; q < 4; ++q){
        float4 av = *reinterpret_cast<const float4*>(&arst[(rh * 4 + q) * 1024 + d4]);
        a[q][0] = fmaf(w4.x, av.x, a[q][0]); a[q][1] = fmaf(w4.y, av.y, a[q][1]);
        a[q][2] = fmaf(w4.z, av.z, a[q][2]); a[q][3] = fmaf(w4.w, av.w, a[q][3]);
      }
    }
    const double bb = (double)fc1b[o];
    #pragma unroll
    for (int q = 0; q < 4; ++q)
      z[q] = ((double)a[q][0] + (double)a[q][1]) + ((double)a[q][2] + (double)a[q][3]) + bb;
  }
  __syncthreads();

  // key_feat tiles -> LDS, float4-slot XOR swizzle (slot ^= e&7) to break stride-128B bank alias
  #pragma unroll
  for (int j = 0; j < 16; ++j){
    int f = t + 512 * j;                 // 8192 float4s
    int r = f >> 10, rem = f & 1023;
    int e = rem >> 3, sl = rem & 7;
    float4 v = *reinterpret_cast<const float4*>(&kfg[((blkrow + r) * 128 + e) * 32 + sl * 4]);
    kf4[(r * 128 + e) * 8 + (sl ^ (e & 7))] = v;
  }

  // register preloads
  float m2rf[32];
  #pragma unroll
  for (int k = 0; k < 32; ++k) m2rf[k] = (float)m2g[o * 32 + k];
  const double vpbr = vpbg[o];
  float4 w4r[16];
  #pragma unroll
  for (int j = 0; j < 16; ++j)
    w4r[j] = *reinterpret_cast<const float4*>(&wih[g * 256 + sh * 64 + j * 4]);
  float whr[8];
  #pragma unroll
  for (int jk = 0; jk < 8; ++jk) whr[jk] = whh[g * 32 + sh * 8 + jk];
  const double bsum = (double)bih[g] + (double)bhh[g];

  // ---- mask load with dtype auto-detect (bool as u8 bytes vs 32-bit words) ----
  uint64_t m0, m1;
  {
    const uint32_t w0 = *(const uint32_t*)selmask;
    if (w0 == 0x01010101u){
      const uint8_t* m8 = (const uint8_t*)selmask;
      m0 = __ballot(m8[(blkrow + w) * 128 + ln] != 0);
      m1 = __ballot(m8[(blkrow + w) * 128 + 64 + ln] != 0);
    } else {
      const uint32_t* m32 = (const uint32_t*)selmask;
      m0 = __ballot(m32[(blkrow + w) * 128 + ln] != 0);
      m1 = __ballot(m32[(blkrow + w) * 128 + 64 + ln] != 0);
    }
  }
  bool  isend = false;
  float selnum = (float)NSTEPS;   // used by ln==0
  double cnt_reg = 0.0;           // ln==0
  float  c_regf = 0.f;            // lanes < 32 (k = ln); f32 cell state (ref is f32 too)
  double sacc_reg = 0.0;          // lanes < 32
  if (ln < 32){ hld[w * 32 + ln] = 0.0; hf[w * 32 + ln] = 0.f; }
  __syncthreads();

  #pragma unroll 1
  for (int i = 0; i < NSTEPS; ++i){
    // --- A: x = relu(z) -> LDS (f32, matching reference quantization point) ---
    #pragma unroll
    for (int q = 0; q < 4; ++q){
      double zv = z[q];
      float xv = zv > 0.0 ? (float)zv : 0.0f;
      xk[(rh * 4 + q) * 288 + (o >> 5) * 36 + (o & 31)] = xv;
    }
    __syncthreads();

    // --- B: gates = w_ih@x + w_hh@h + b  (all-f32 chains + f32 combine;
    //     gl store casts to f64 — gl dtype unchanged, C/D untouched) ---
    {
      float acc[8] = {0.f,0.f,0.f,0.f,0.f,0.f,0.f,0.f};
      #pragma unroll
      for (int i4 = 0; i4 < 64; i4 += 4){
        const int d = sh * 64 + i4;
        const int xi = (d >> 5) * 36 + (d & 31);
        const float4 w4 = w4r[i4 >> 2];
        #pragma unroll
        for (int r = 0; r < 8; ++r){
          float4 xv = *reinterpret_cast<const float4*>(&xk[r * 288 + xi]);
          acc[r] = fmaf(w4.x, xv.x, fmaf(w4.y, xv.y, fmaf(w4.z, xv.z, fmaf(w4.w, xv.w, acc[r]))));
        }
      }
      #pragma unroll
      for (int r = 0; r < 8; ++r){
        float hacc = 0.f;
        #pragma unroll
        for (int q2 = 0; q2 < 2; ++q2){
          float4 hv = *reinterpret_cast<const float4*>(&hf[r * 32 + sh * 8 + q2 * 4]);
          const float* wp = &whr[q2 * 4];
          hacc = fmaf(wp[0], hv.x, fmaf(wp[1], hv.y,
                 fmaf(wp[2], hv.z, fmaf(wp[3], hv.w, hacc))));
        }
        acc[r] += hacc;
      }
      #pragma unroll
      for (int r = 0; r < 8; ++r){
        acc[r] += __shfl_xor(acc[r], 1);
        acc[r] += __shfl_xor(acc[r], 2);
      }
      if (sh == 0){
        #pragma unroll
        for (int r = 0; r < 8; ++r) gl[r * 128 + g] = (double)acc[r] + bsum;
      }
    }
    __syncthreads();

    // --- C: LSTM pointwise in f32 (v_exp_f32; R10/R11-validated). Publishes f64+f32 h. ---
    if (ln < 32){
      const int k = ln;
      float gi = (float)gl[w * 128 + k],      gf = (float)gl[w * 128 + 32 + k];
      float gc = (float)gl[w * 128 + 64 + k], go = (float)gl[w * 128 + 96 + k];
      float ig = 1.f / (1.f + __expf(-gi));
      float fg = 1.f / (1.f + __expf(-gf));
      float og = 1.f / (1.f + __expf(-go));
      float tg = 2.f / (1.f + __expf(-2.f * gc)) - 1.f;     // tanh(gg)
      c_regf = fg * c_regf + ig * tg;
      float tc = 2.f / (1.f + __expf(-2.f * c_regf)) - 1.f; // tanh(c)
      float hv = og * tc;
      hld[w * 32 + k] = (double)hv;
      hf[w * 32 + k] = hv;
    }
    __syncthreads();

    // --- D: logits (f64) + masked-logits output write (R11/R15 byte-identical) ---
    double lg[2];
    const size_t lbase = ((size_t)(blkrow + w) * NSTEPS + i) * 128;
    #pragma unroll
    for (int j = 0; j < 2; ++j){
      const int e = ln + 64 * j;
      const int sw = e & 7;
      const int base = (w * 128 + e) * 8;
      double acc = 0.0;
      #pragma unroll
      for (int l = 0; l < 8; ++l){
        float4 v = kf4[base + (l ^ sw)];
        const double* hp = &hld[w * 32 + l * 4];
        acc = fma((double)v.x, hp[0], acc);
        acc = fma((double)v.y, hp[1], acc);
        acc = fma((double)v.z, hp[2], acc);
        acc = fma((double)v.w, hp[3], acc);
      }
      lg[j] = acc;
      bool bit = (j == 0) ? ((m0 >> e) & 1ull) : ((m1 >> (e - 64)) & 1ull);
      outp[OUT_L0 + lbase + e] = bit ? (float)acc : NEGV;
    }

    // --- E: gumbel-argmax in f32 (R15-validated; thread-local leaf region) ---
    float bs = -3.0e38f; int bi = 1 << 20;
    const uint2 kk = keys[i];
    #pragma unroll
    for (int j = 0; j < 2; ++j){
      const int e = ln + 64 * j;
      bool bit = (j == 0) ? ((m0 >> e) & 1ull) : ((m1 >> (e - 64)) & 1ull);
      if (bit){
        uint32_t bits = jax_bits(kk.x, kk.y, (uint32_t)((blkrow + w) * 128 + e));
        float sv = (float)lg[j] + gumbel_bits_f32(bits);
        if (sv > bs || (sv == bs && e < bi)){ bs = sv; bi = e; }
      }
    }
    #pragma unroll
    for (int m = 1; m < 64; m <<= 1){
      float os = __shfl_xor(bs, m);
      int   oi = __shfl_xor(bi, m);
      if (os > bs || (os == bs && oi < bi)){ bs = os; bi = oi; }
    }
    const int uid = bi;

    // --- F: state updates (R11-exact; publishes f32 out-vec for G) ---
    {
      const bool new_end = (uid == 127);
      if (ln == 0 && new_end && !isend) selnum = (float)i;
      isend = isend || new_end;
      const double gate = isend ? 0.0 : 1.0;
      if (uid < 64) m0 &= ~(1ull << uid); else m1 &= ~(1ull << (uid - 64));
      if (ln == 0){
        gted[w] = gate;
        cnt_reg += gate;
        outp[OUT_U0 + (size_t)(blkrow + w) * NSTEPS + i] = (float)uid;
      }
      if (ln < 32){
        const int k = ln;
        float4 v = kf4[(w * 128 + uid) * 8 + ((k >> 2) ^ (uid & 7))];
        const int s3 = k & 3;
        float kv = (s3 == 0) ? v.x : (s3 == 1) ? v.y : (s3 == 2) ? v.z : v.w;
        double ov = (double)kv - kav[w * 32 + k];
        ovf[w * 32 + k] = (float)ov;
        sacc_reg += gate * ov;
      }
    }
    __syncthreads();

    // --- G: z += gate*(M2[o,:]·out + v_pb[o])  (f32 delta + f64 carry — R11-exact) ---
    #pragma unroll
    for (int q = 0; q < 4; ++q){
      const int r = rh * 4 + q;
      if (gted[r] != 0.0){
        float zf = 0.f;
        #pragma unroll
        for (int j8 = 0; j8 < 8; ++j8){
          float4 ov4 = *reinterpret_cast<const float4*>(&ovf[r * 32 + j8 * 4]);  // uniform
          const float* mp = &m2rf[j8 * 4];
          zf = fmaf(mp[0], ov4.x, fmaf(mp[1], ov4.y,
               fmaf(mp[2], ov4.z, fmaf(mp[3], ov4.w, zf))));
        }
        z[q] += (double)zf + vpbr;
      }
    }
    __syncthreads();
  }

  // -------- epilogue: sel_num, s_acc publish, final ar --------
  if (ln < 32) ovd[w * 32 + ln] = sacc_reg;
  if (ln == 0){
    cntd[w] = cnt_reg;
    outp[OUT_S0 + (blkrow + w)] = selnum;
  }
  __syncthreads();

  #pragma unroll
  for (int jj = 0; jj < 2; ++jj){
    const int dd = t * 2 + jj;
    float4 pw4[8];
    #pragma unroll
    for (int q = 0; q < 8; ++q)
      pw4[q] = *reinterpret_cast<const float4*>(&projw[dd * 32 + q * 4]);
    const double pb = (double)projb[dd];
    #pragma unroll
    for (int r = 0; r < 8; ++r){
      const double* sp = &ovd[r * 32];
      double acc = 0.0;
      #pragma unroll
      for (int q = 0; q < 8; ++q){
        acc = fma((double)pw4[q].x, sp[q * 4 + 0], acc);
        acc = fma((double)pw4[q].y, sp[q * 4 + 1], acc);
        acc = fma((double)pw4[q].z, sp[q * 4 + 2], acc);
        acc = fma((double)pw4[q].w, sp[q * 4 + 3], acc);
      }
      double arv = (double)ar0[(blkrow + r) * 1024 + dd] + acc + pb * cntd[r];
      outp[OUT_A0 + (size_t)(blkrow + r) * 1024 + dd] = (float)arv;
    }
  }
}

// ---------------- launcher ----------------
extern "C" void kernel_launch(void* const* d_in, const int* in_sizes, int n_in,
                              void* d_out, int out_size, void* d_ws, size_t ws_size,
                              hipStream_t stream){
  const float*   ar0   = (const float*)d_in[0];
  const float*   ee    = (const float*)d_in[1];
  const void*    msk   = (const void*)d_in[2];
  const float*   unum  = (const float*)d_in[3];
  const float*   convw = (const float*)d_in[4];
  const float*   convb = (const float*)d_in[5];
  const float*   fc1w  = (const float*)d_in[6];
  const float*   fc1b  = (const float*)d_in[7];
  const float*   wih   = (const float*)d_in[8];
  const float*   whh   = (const float*)d_in[9];
  const float*   bih   = (const float*)d_in[10];
  const float*   bhh   = (const float*)d_in[11];
  const float*   projw = (const float*)d_in[12];
  const float*   projb = (const float*)d_in[13];
  float* out = (float*)d_out;
  char*  ws  = (char*)d_ws;

  float*  kf  = (float*) (ws + WS_KF);
  double* ka  = (double*)(ws + WS_KA);
  double* m2  = (double*)(ws + WS_M2);
  double* vpb = (double*)(ws + WS_VPB);

  k_keyfeat<<<2048, 256, 0, stream>>>(ee, convw, convb, kf);
  k_keyavg <<<512, 256, 0, stream>>>(kf, unum, ka);
  k_m2     <<<33, 256, 0, stream>>>(fc1w, projw, projb, m2, vpb);

  (void)hipFuncSetAttribute((const void*)k_scan,
                            hipFuncAttributeMaxDynamicSharedMemorySize, SM_SIZE);
  k_scan<<<512, 512, SM_SIZE, stream>>>(ar0, msk, fc1w, fc1b, wih, whh, bih, bhh,
                                        projw, projb, kf, ka, m2, vpb, out);
}